// Round 2
// baseline (773.933 us; speedup 1.0000x reference)
//
#include <hip/hip_runtime.h>
#include <hip/hip_bf16.h>

#define NN 10000
#define NE 640000
#define NF 128
#define NH 128
#define NT 128
#define KA 256   // NF + NH
#define LN_EPS 1e-5f

typedef __bf16 bf16x8 __attribute__((ext_vector_type(8)));
typedef float floatx4 __attribute__((ext_vector_type(4)));
typedef float nfloat4 __attribute__((ext_vector_type(4)));

__device__ inline unsigned short f2bf(float f) {
    unsigned int u = __float_as_uint(f);
    u += 0x7FFFu + ((u >> 16) & 1u);   // round-to-nearest-even
    return (unsigned short)(u >> 16);
}

__device__ inline bf16x8 load_frag(const unsigned short* p) {
    uint4 u = *(const uint4*)p;
    return __builtin_bit_cast(bf16x8, u);
}

// native casts -> compiler emits v_cvt_pk_bf16_f32 (RTNE), 2 floats/instr
__device__ inline bf16x8 cvt8(nfloat4 v0, nfloat4 v1) {
    bf16x8 r;
    r[0] = (__bf16)v0.x; r[1] = (__bf16)v0.y; r[2] = (__bf16)v0.z; r[3] = (__bf16)v0.w;
    r[4] = (__bf16)v1.x; r[5] = (__bf16)v1.y; r[6] = (__bf16)v1.z; r[7] = (__bf16)v1.w;
    return r;
}

// ---------------------------------------------------------------------------
// Prologue: pack weights f32 [K][N] -> bf16 MFMA-fragment-major order.
// Fragment f=(ct*nks+ks): 64 lanes x 8 elems contiguous (1KB). Lane l holds
// B[k = ks*32 + (l>>4)*8 + j][n = ct*16 + (l&15)]  -> coalesced load_frag.
// ---------------------------------------------------------------------------
__global__ __launch_bounds__(256) void conv_weights(
    const float* __restrict__ W1a, const float* __restrict__ W1b,
    const float* __restrict__ W2a, const float* __restrict__ W2b,
    unsigned short* __restrict__ wp1a, unsigned short* __restrict__ wp1b,
    unsigned short* __restrict__ wp2a, unsigned short* __restrict__ wp2b)
{
    int tid = blockIdx.x * 256 + threadIdx.x;
    const float* src;
    unsigned short* dst;
    int t, nks;
    if (tid < 4096)        { src = W1a; dst = wp1a; t = tid;         nks = 8; }
    else if (tid < 6144)   { src = W1b; dst = wp1b; t = tid - 4096;  nks = 4; }
    else if (tid < 10240)  { src = W2a; dst = wp2a; t = tid - 6144;  nks = 8; }
    else if (tid < 12288)  { src = W2b; dst = wp2b; t = tid - 10240; nks = 4; }
    else return;

    const int f = t >> 6, l = t & 63;
    const int ct = f / nks, ks = f - ct * nks;
    const int n  = ct * 16 + (l & 15);
    const int k0 = ks * 32 + (l >> 4) * 8;
    unsigned short tmp[8];
#pragma unroll
    for (int j = 0; j < 8; ++j)
        tmp[j] = f2bf(src[(k0 + j) * 128 + n]);
    *(uint4*)&dst[t * 8] = *(const uint4*)tmp;
}

// ---------------------------------------------------------------------------
// Counting sort by target row: hist -> scan -> scatter.
// ---------------------------------------------------------------------------
__global__ __launch_bounds__(256) void hist_kernel(
    const int* __restrict__ row, int* __restrict__ hist)
{
    int e = blockIdx.x * 256 + threadIdx.x;
    if (e < NE) atomicAdd(&hist[row[e]], 1);
}

__global__ __launch_bounds__(256) void scan_kernel(
    const int* __restrict__ hist, int* __restrict__ row_start,
    int* __restrict__ cursor)
{
    __shared__ int partials[256];
    const int t = threadIdx.x;
    const int base = t * 40;                  // 256*40 = 10240 >= NN
    int s = 0;
    for (int i = 0; i < 40; ++i) {
        int b = base + i;
        if (b < NN) s += hist[b];
    }
    partials[t] = s;
    __syncthreads();
    int pre = 0;
    for (int i = 0; i < t; ++i) pre += partials[i];
    int run = pre;
    for (int i = 0; i < 40; ++i) {
        int b = base + i;
        if (b < NN) {
            row_start[b] = run;
            cursor[b] = run;
            run += hist[b];
        }
    }
    if (t == 255) row_start[NN] = NE;
}

__global__ __launch_bounds__(256) void scatter_kernel(
    const int* __restrict__ row, int* __restrict__ cursor,
    int* __restrict__ perm)
{
    int e = blockIdx.x * 256 + threadIdx.x;
    if (e < NE) {
        int p = atomicAdd(&cursor[row[e]], 1);
        perm[p] = e;
    }
}

// ---------------------------------------------------------------------------
// Edge MLP "regA": per-wave 16 sorted edges, A-fragments built DIRECTLY in
// registers from global (no LDS A staging, no stage barrier). LDS = one 32KB
// accbuf; each wave's private 8KB chunk doubles as its Ttile (GEMM2
// transpose) before being overwritten by that wave's f32 GEMM2 output.
// Exactly ONE __syncthreads per block (before the cross-wave reduction).
// 33KB LDS -> 4 blocks/CU (was 3), __launch_bounds__(256,4) caps VGPR at 128.
// b1b moved to node kernel (mean(v+b) = mean(v)+b).
// ---------------------------------------------------------------------------
__global__ __launch_bounds__(256, 4) void edge_mlp_kernel(
    const float* __restrict__ x,
    const int* __restrict__ erow, const int* __restrict__ ecol,
    const float* __restrict__ eattr,
    const int* __restrict__ perm,
    const unsigned short* __restrict__ wp1a, const float* __restrict__ b1a,
    const float* __restrict__ g1, const float* __restrict__ be1,
    const unsigned short* __restrict__ wp1b,
    float* __restrict__ sums)
{
    __shared__ __align__(16) float accbuf[64 * 128];   // 32768 B
    __shared__ int rows_s[64];                         // 256 B

    const int wave = threadIdx.x >> 6;
    const int lane = threadIdx.x & 63;
    const int lm   = lane & 15;
    const int lq4  = lane >> 4;
    const int e0   = blockIdx.x * 64;

    if (threadIdx.x < 64)
        rows_s[threadIdx.x] = erow[perm[e0 + threadIdx.x]];

    // ---- A-fragments straight from global: lane holds row lm (this wave's
    // edge), k = ks*32 + lq4*8 .. +8.  4 lanes cover 128B contiguous per edge
    // per fragment -> same coalescing as the old LDS path, zero LDS traffic.
    const int e    = perm[e0 + wave * 16 + lm];
    const int scol = ecol[e];
    const nfloat4* xr = (const nfloat4*)(x + (size_t)scol * NF) + lq4 * 2;
    const nfloat4* ar = (const nfloat4*)(eattr + (size_t)e * NH) + lq4 * 2;

    bf16x8 a1[8];
#pragma unroll
    for (int ks = 0; ks < 4; ++ks) {
        nfloat4 v0 = xr[ks * 8];
        nfloat4 v1 = xr[ks * 8 + 1];
        a1[ks] = cvt8(v0, v1);
    }
#pragma unroll
    for (int ks = 0; ks < 4; ++ks) {
        nfloat4 v0 = __builtin_nontemporal_load(ar + ks * 8);
        nfloat4 v1 = __builtin_nontemporal_load(ar + ks * 8 + 1);
        a1[4 + ks] = cvt8(v0, v1);
    }

    // ---- GEMM1: [16 x 256] @ [256 x 128], B frag-packed in L2 ----
    floatx4 acc1[8];
#pragma unroll
    for (int ct = 0; ct < 8; ++ct) {
        floatx4 acc = {0.f, 0.f, 0.f, 0.f};
        const unsigned short* wr = wp1a + (ct * 8 * 64 + lane) * 8;
#pragma unroll
        for (int ks = 0; ks < 8; ++ks) {
            bf16x8 b = load_frag(wr + ks * 512);
            acc = __builtin_amdgcn_mfma_f32_16x16x32_bf16(a1[ks], b, acc, 0, 0, 0);
        }
        acc1[ct] = acc;
    }

    // ---- bias + ReLU + per-wave LayerNorm (shuffle reduce over 16 lanes) ----
    float sum_[4] = {0, 0, 0, 0}, sq_[4] = {0, 0, 0, 0};
#pragma unroll
    for (int ct = 0; ct < 8; ++ct) {
        const float bb = b1a[ct * 16 + lm];
#pragma unroll
        for (int i = 0; i < 4; ++i) {
            float v = acc1[ct][i] + bb;
            v = fmaxf(v, 0.f);
            acc1[ct][i] = v;
            sum_[i] += v;
            sq_[i]  += v * v;
        }
    }
#pragma unroll
    for (int m = 1; m < 16; m <<= 1) {
#pragma unroll
        for (int i = 0; i < 4; ++i) {
            sum_[i] += __shfl_xor(sum_[i], m, 64);
            sq_[i]  += __shfl_xor(sq_[i],  m, 64);
        }
    }
    float mu[4], rs[4];
#pragma unroll
    for (int i = 0; i < 4; ++i) {
        mu[i] = sum_[i] * (1.f / NH);
        float var = sq_[i] * (1.f / NH) - mu[i] * mu[i];
        rs[i] = rsqrtf(var + LN_EPS);
    }

    // ---- LN apply -> per-wave Ttile (aliases this wave's accbuf chunk) ----
    unsigned short* Tw = (unsigned short*)(accbuf + wave * 16 * 128); // 8KB chunk
#pragma unroll
    for (int ct = 0; ct < 8; ++ct) {
        const int c = ct * 16 + lm;
        const float gg = g1[c], bb = be1[c];
#pragma unroll
        for (int i = 0; i < 4; ++i) {
            float nv = (acc1[ct][i] - mu[i]) * rs[i] * gg + bb;
            Tw[(lq4 * 4 + i) * 136 + c] = __builtin_bit_cast(unsigned short, (__bf16)nv);
        }
    }
    asm volatile("" ::: "memory");   // keep compiler from reordering the alias

    // a2 fully into regs BEFORE any accbuf write (data-dep guarantees order)
    bf16x8 a2[4];
#pragma unroll
    for (int ks = 0; ks < 4; ++ks)
        a2[ks] = load_frag(&Tw[lm * 136 + ks * 32 + lq4 * 8]);

    // ---- GEMM2: [16 x 128] @ [128 x 128] -> f32 into rotated accbuf ----
#pragma unroll
    for (int ct = 0; ct < 8; ++ct) {
        floatx4 acc = {0.f, 0.f, 0.f, 0.f};
        const unsigned short* wr = wp1b + (ct * 4 * 64 + lane) * 8;
#pragma unroll
        for (int ks = 0; ks < 4; ++ks) {
            bf16x8 b = load_frag(wr + ks * 512);
            acc = __builtin_amdgcn_mfma_f32_16x16x32_bf16(a2[ks], b, acc, 0, 0, 0);
        }
        const int c = ct * 16 + lm;
#pragma unroll
        for (int i = 0; i < 4; ++i) {
            const int r = wave * 16 + lq4 * 4 + i;
            accbuf[r * 128 + ((c + r * 4) & 127)] = acc[i];
        }
    }
    __syncthreads();

    // ---- segmented reduction over the block's 64 sorted edges ----
    {
        const int t = threadIdx.x;
        const int cc = t & 127;
        const int jb = (t >> 7) * 32;
        float a = 0.f;
        int cur = rows_s[jb];
#pragma unroll 4
        for (int j = jb; j < jb + 32; ++j) {
            a += accbuf[j * 128 + ((cc + j * 4) & 127)];
            int nxt = (j + 1 < jb + 32) ? rows_s[j + 1] : -1;
            if (nxt != cur) {
                atomicAdd(&sums[cur * NH + cc], a);
                a = 0.f;
                cur = nxt;
            }
        }
    }
}

// ---------------------------------------------------------------------------
// Node MLP: A = [x[n] | sums[n]/cnt + b1b (cnt>0)], packed weights.
// ---------------------------------------------------------------------------
__global__ __launch_bounds__(256) void node_mlp_kernel(
    const float* __restrict__ x,
    const float* __restrict__ sums, const int* __restrict__ row_start,
    const float* __restrict__ b1b,
    const unsigned short* __restrict__ wp2a, const float* __restrict__ b2a,
    const float* __restrict__ g2, const float* __restrict__ be2,
    const unsigned short* __restrict__ wp2b, const float* __restrict__ b2b,
    float* __restrict__ out)
{
    __shared__ unsigned short Atile[4][16][KA + 8];
    __shared__ unsigned short Ttile[4][16][NH + 8];

    const int wave = threadIdx.x >> 6;
    const int lane = threadIdx.x & 63;
    const int n0 = blockIdx.x * 64 + wave * 16;

    {
        const int lrow = lane >> 2;
        const int lq   = lane & 3;
        int n = n0 + lrow;
        if (n >= NN) n = NN - 1;
        const int cntn = row_start[n + 1] - row_start[n];
        const float inv  = (cntn > 0) ? (1.f / (float)cntn) : 1.f;
        const float addb = (cntn > 0) ? 1.f : 0.f;
        const float4* xr = (const float4*)(x + n * NF);
        const float4* sr = (const float4*)(sums + n * NH);
        const float4* br = (const float4*)b1b;
        unsigned short* Ar = &Atile[wave][lrow][0];
#pragma unroll
        for (int it = 0; it < 8; ++it) {
            int c4 = lq + it * 4;
            float4 v = xr[c4];
            uint2 w;
            w.x = (unsigned)f2bf(v.x) | ((unsigned)f2bf(v.y) << 16);
            w.y = (unsigned)f2bf(v.z) | ((unsigned)f2bf(v.w) << 16);
            *(uint2*)&Ar[c4 * 4] = w;
            float4 v2 = sr[c4];
            float4 bv = br[c4];
            float a0 = v2.x * inv + addb * bv.x;
            float a1 = v2.y * inv + addb * bv.y;
            float a2 = v2.z * inv + addb * bv.z;
            float a3 = v2.w * inv + addb * bv.w;
            uint2 w2;
            w2.x = (unsigned)f2bf(a0) | ((unsigned)f2bf(a1) << 16);
            w2.y = (unsigned)f2bf(a2) | ((unsigned)f2bf(a3) << 16);
            *(uint2*)&Ar[128 + c4 * 4] = w2;
        }
    }
    __syncthreads();

    const int lm  = lane & 15;
    const int lq4 = lane >> 4;

    bf16x8 a1[8];
#pragma unroll
    for (int ks = 0; ks < 8; ++ks)
        a1[ks] = load_frag(&Atile[wave][lm][ks * 32 + lq4 * 8]);

    floatx4 acc1[8];
#pragma unroll
    for (int ct = 0; ct < 8; ++ct) {
        floatx4 acc = {0.f, 0.f, 0.f, 0.f};
        const unsigned short* wr = wp2a + (ct * 8 * 64 + lane) * 8;
#pragma unroll
        for (int ks = 0; ks < 8; ++ks) {
            bf16x8 b = load_frag(wr + ks * 512);
            acc = __builtin_amdgcn_mfma_f32_16x16x32_bf16(a1[ks], b, acc, 0, 0, 0);
        }
        acc1[ct] = acc;
    }

    float sum_[4] = {0, 0, 0, 0}, sq_[4] = {0, 0, 0, 0};
#pragma unroll
    for (int ct = 0; ct < 8; ++ct) {
        const float bb = b2a[ct * 16 + lm];
#pragma unroll
        for (int i = 0; i < 4; ++i) {
            float v = acc1[ct][i] + bb;
            v = fmaxf(v, 0.f);
            acc1[ct][i] = v;
            sum_[i] += v;
            sq_[i]  += v * v;
        }
    }
#pragma unroll
    for (int m = 1; m < 16; m <<= 1) {
#pragma unroll
        for (int i = 0; i < 4; ++i) {
            sum_[i] += __shfl_xor(sum_[i], m, 64);
            sq_[i]  += __shfl_xor(sq_[i],  m, 64);
        }
    }
    float mu[4], rs[4];
#pragma unroll
    for (int i = 0; i < 4; ++i) {
        mu[i] = sum_[i] * (1.f / NH);
        float var = sq_[i] * (1.f / NH) - mu[i] * mu[i];
        rs[i] = rsqrtf(var + LN_EPS);
    }
#pragma unroll
    for (int ct = 0; ct < 8; ++ct) {
        const int c = ct * 16 + lm;
        const float gg = g2[c], bb = be2[c];
#pragma unroll
        for (int i = 0; i < 4; ++i) {
            float nv = (acc1[ct][i] - mu[i]) * rs[i] * gg + bb;
            Ttile[wave][lq4 * 4 + i][c] = f2bf(nv);
        }
    }
    __syncthreads();

    bf16x8 a2[4];
#pragma unroll
    for (int ks = 0; ks < 4; ++ks)
        a2[ks] = load_frag(&Ttile[wave][lm][ks * 32 + lq4 * 8]);

#pragma unroll
    for (int ct = 0; ct < 8; ++ct) {
        floatx4 acc = {0.f, 0.f, 0.f, 0.f};
        const unsigned short* wr = wp2b + (ct * 4 * 64 + lane) * 8;
#pragma unroll
        for (int ks = 0; ks < 4; ++ks) {
            bf16x8 b = load_frag(wr + ks * 512);
            acc = __builtin_amdgcn_mfma_f32_16x16x32_bf16(a2[ks], b, acc, 0, 0, 0);
        }
        const int c = ct * 16 + lm;
        const float bb = b2b[c];
#pragma unroll
        for (int i = 0; i < 4; ++i) {
            int n = n0 + lq4 * 4 + i;
            if (n < NN) out[n * NT + c] = acc[i] + bb;
        }
    }
}

// ---------------------------------------------------------------------------
// Workspace layout (bytes):
//   [0,          5,120,000)  sums      f32 [10000][128]
//   [5,120,000,  5,160,000)  hist      int [10000]
//   [5,160,000,  5,200,000)  cursor    int [10000]
//   [5,200,000,  5,240,064)  row_start int [10001] (padded)
//   [5,240,064,  7,800,064)  perm      int [640000]
//   [7,800,064,  7,865,600)  wp1a      bf16 frag-packed [64 frags][64 lanes][8]
//   [7,865,600,  7,898,368)  wp1b      bf16 frag-packed [32][64][8]
//   [7,898,368,  7,963,904)  wp2a      bf16 frag-packed [64][64][8]
//   [7,963,904,  7,996,672)  wp2b      bf16 frag-packed [32][64][8]
// ---------------------------------------------------------------------------
extern "C" void kernel_launch(void* const* d_in, const int* in_sizes, int n_in,
                              void* d_out, int out_size, void* d_ws, size_t ws_size,
                              hipStream_t stream) {
    const float* x     = (const float*)d_in[0];
    const int*   eidx  = (const int*)d_in[1];
    const float* eattr = (const float*)d_in[2];
    const float* W1a = (const float*)d_in[3];
    const float* b1a = (const float*)d_in[4];
    const float* g1  = (const float*)d_in[5];
    const float* be1 = (const float*)d_in[6];
    const float* W1b = (const float*)d_in[7];
    const float* b1b = (const float*)d_in[8];
    const float* W2a = (const float*)d_in[9];
    const float* b2a = (const float*)d_in[10];
    const float* g2  = (const float*)d_in[11];
    const float* be2 = (const float*)d_in[12];
    const float* W2b = (const float*)d_in[13];
    const float* b2b = (const float*)d_in[14];

    char* ws = (char*)d_ws;
    float* sums     = (float*)ws;
    int*   hist     = (int*)(ws + 5120000);
    int*   cursor   = (int*)(ws + 5160000);
    int*   row_start= (int*)(ws + 5200000);
    int*   perm     = (int*)(ws + 5240064);
    unsigned short* wp1a = (unsigned short*)(ws + 7800064);
    unsigned short* wp1b = (unsigned short*)(ws + 7865600);
    unsigned short* wp2a = (unsigned short*)(ws + 7898368);
    unsigned short* wp2b = (unsigned short*)(ws + 7963904);

    const int* erow = eidx;
    const int* ecol = eidx + NE;

    (void)hipMemsetAsync(ws, 0, 5160000, stream);   // zero sums + hist
    conv_weights<<<48, 256, 0, stream>>>(W1a, W1b, W2a, W2b, wp1a, wp1b, wp2a, wp2b);
    hist_kernel<<<(NE + 255) / 256, 256, 0, stream>>>(erow, hist);
    scan_kernel<<<1, 256, 0, stream>>>(hist, row_start, cursor);
    scatter_kernel<<<(NE + 255) / 256, 256, 0, stream>>>(erow, cursor, perm);
    edge_mlp_kernel<<<NE / 64, 256, 0, stream>>>(x, erow, ecol, eattr, perm,
                                                 wp1a, b1a, g1, be1, wp1b, sums);
    node_mlp_kernel<<<(NN + 63) / 64, 256, 0, stream>>>(x, sums, row_start, b1b,
                                                        wp2a, b2a, g2, be2, wp2b, b2b,
                                                        (float*)d_out);
}

// Round 3
// 732.960 us; speedup vs baseline: 1.0559x; 1.0559x over previous
//
#include <hip/hip_runtime.h>
#include <hip/hip_bf16.h>

#define NN 10000
#define NE 640000
#define NF 128
#define NH 128
#define NT 128
#define KA 256   // NF + NH
#define LN_EPS 1e-5f

typedef __bf16 bf16x8 __attribute__((ext_vector_type(8)));
typedef float floatx4 __attribute__((ext_vector_type(4)));
typedef float nfloat4 __attribute__((ext_vector_type(4)));

__device__ inline unsigned short f2bf(float f) {
    unsigned int u = __float_as_uint(f);
    u += 0x7FFFu + ((u >> 16) & 1u);   // round-to-nearest-even
    return (unsigned short)(u >> 16);
}

__device__ inline bf16x8 load_frag(const unsigned short* p) {
    uint4 u = *(const uint4*)p;
    return __builtin_bit_cast(bf16x8, u);
}

// native casts -> v_cvt_pk_bf16_f32 (RTNE), 2 floats/instr
__device__ inline bf16x8 cvt8(nfloat4 v0, nfloat4 v1) {
    bf16x8 r;
    r[0] = (__bf16)v0.x; r[1] = (__bf16)v0.y; r[2] = (__bf16)v0.z; r[3] = (__bf16)v0.w;
    r[4] = (__bf16)v1.x; r[5] = (__bf16)v1.y; r[6] = (__bf16)v1.z; r[7] = (__bf16)v1.w;
    return r;
}

// wave-local LDS ordering fence: all prior ds_writes complete before any
// later ds_read issues; "memory" clobber stops compiler reordering.
__device__ inline void lds_fence() {
    asm volatile("s_waitcnt lgkmcnt(0)" ::: "memory");
}

// ---------------------------------------------------------------------------
// Prologue: pack weights f32 [K][N] -> bf16 MFMA-fragment-major order.
// Fragment f=(ct*nks+ks): 64 lanes x 8 elems contiguous (1KB). Lane l holds
// B[k = ks*32 + (l>>4)*8 + j][n = ct*16 + (l&15)]  -> coalesced load_frag.
// ---------------------------------------------------------------------------
__global__ __launch_bounds__(256) void conv_weights(
    const float* __restrict__ W1a, const float* __restrict__ W1b,
    const float* __restrict__ W2a, const float* __restrict__ W2b,
    unsigned short* __restrict__ wp1a, unsigned short* __restrict__ wp1b,
    unsigned short* __restrict__ wp2a, unsigned short* __restrict__ wp2b)
{
    int tid = blockIdx.x * 256 + threadIdx.x;
    const float* src;
    unsigned short* dst;
    int t, nks;
    if (tid < 4096)        { src = W1a; dst = wp1a; t = tid;         nks = 8; }
    else if (tid < 6144)   { src = W1b; dst = wp1b; t = tid - 4096;  nks = 4; }
    else if (tid < 10240)  { src = W2a; dst = wp2a; t = tid - 6144;  nks = 8; }
    else if (tid < 12288)  { src = W2b; dst = wp2b; t = tid - 10240; nks = 4; }
    else return;

    const int f = t >> 6, l = t & 63;
    const int ct = f / nks, ks = f - ct * nks;
    const int n  = ct * 16 + (l & 15);
    const int k0 = ks * 32 + (l >> 4) * 8;
    unsigned short tmp[8];
#pragma unroll
    for (int j = 0; j < 8; ++j)
        tmp[j] = f2bf(src[(k0 + j) * 128 + n]);
    *(uint4*)&dst[t * 8] = *(const uint4*)tmp;
}

// ---------------------------------------------------------------------------
// Counting sort by target row: hist -> scan -> scatter.
// ---------------------------------------------------------------------------
__global__ __launch_bounds__(256) void hist_kernel(
    const int* __restrict__ row, int* __restrict__ hist)
{
    int e = blockIdx.x * 256 + threadIdx.x;
    if (e < NE) atomicAdd(&hist[row[e]], 1);
}

__global__ __launch_bounds__(256) void scan_kernel(
    const int* __restrict__ hist, int* __restrict__ row_start,
    int* __restrict__ cursor)
{
    __shared__ int partials[256];
    const int t = threadIdx.x;
    const int base = t * 40;                  // 256*40 = 10240 >= NN
    int s = 0;
    for (int i = 0; i < 40; ++i) {
        int b = base + i;
        if (b < NN) s += hist[b];
    }
    partials[t] = s;
    __syncthreads();
    int pre = 0;
    for (int i = 0; i < t; ++i) pre += partials[i];
    int run = pre;
    for (int i = 0; i < 40; ++i) {
        int b = base + i;
        if (b < NN) {
            row_start[b] = run;
            cursor[b] = run;
            run += hist[b];
        }
    }
    if (t == 255) row_start[NN] = NE;
}

__global__ __launch_bounds__(256) void scatter_kernel(
    const int* __restrict__ row, int* __restrict__ cursor,
    int* __restrict__ perm)
{
    int e = blockIdx.x * 256 + threadIdx.x;
    if (e < NE) {
        int p = atomicAdd(&cursor[row[e]], 1);
        perm[p] = e;
    }
}

// ---------------------------------------------------------------------------
// Edge MLP, "R0-slim": proven R0 dataflow (LDS transpose-stage, per-wave 16
// edges, all 128 cols) with all intermediates ALIASED into one 33.8KB buffer.
// Every phase is per-wave-private (wave W only touches rows [W*16,W*16+16)),
// so the two early __syncthreads become wave-local lgkmcnt fences; the only
// true barrier is before the cross-wave segmented reduction.
// LDS 51.7KB -> 34KB: 4 blocks/CU (16 waves, was 12).
// smem views (row r = edge slot 0..63):
//   Atile  : shorts, row stride 264, cols 0..255   (staged [x|eattr] bf16)
//   Ttile  : shorts, row stride 264, cols 0..127   (overwrites dead Atile)
//   accbuf : f32,    row stride 132, cols 0..127   (GEMM2 out, reduction)
// b1b moved to node kernel (mean(v+b) = mean(v)+b).
// ---------------------------------------------------------------------------
__global__ __launch_bounds__(256, 4) void edge_mlp_kernel(
    const float* __restrict__ x,
    const int* __restrict__ erow, const int* __restrict__ ecol,
    const float* __restrict__ eattr,
    const int* __restrict__ perm,
    const unsigned short* __restrict__ wp1a, const float* __restrict__ b1a,
    const float* __restrict__ g1, const float* __restrict__ be1,
    const unsigned short* __restrict__ wp1b,
    float* __restrict__ sums)
{
    __shared__ __align__(16) float smem[64 * 132];   // 33792 B, aliased
    __shared__ int rows_s[64];                       // 256 B

    const int wave = threadIdx.x >> 6;
    const int lane = threadIdx.x & 63;
    const int lm   = lane & 15;
    const int lq4  = lane >> 4;
    const int e0   = blockIdx.x * 64;

    if (threadIdx.x < 64)
        rows_s[threadIdx.x] = erow[perm[e0 + threadIdx.x]];

    // ---- preload GEMM1 ct=0 B-frags: oldest in queue, in flight all stage ----
    bf16x8 bpre[8];
#pragma unroll
    for (int ks = 0; ks < 8; ++ks)
        bpre[ks] = load_frag(&wp1a[(ks * 64 + lane) * 8]);

    // ---- stage A = [x[col[e]] | edge_attr[e]] bf16 into own chunk ----
    unsigned short* At = (unsigned short*)smem;
    {
        const int lrow = lane >> 2;          // 0..15: edge slot within wave
        const int lq   = lane & 3;
        const int e = perm[e0 + wave * 16 + lrow];
        const int scol = ecol[e];
        const nfloat4* xr = (const nfloat4*)(x + (size_t)scol * NF);
        const nfloat4* ar = (const nfloat4*)(eattr + (size_t)e * NH);
        unsigned short* Ar = At + (wave * 16 + lrow) * 264;
#pragma unroll
        for (int it = 0; it < 4; ++it) {
            const int g = lq + it * 4;       // 16B granule 0..15
            nfloat4 v0 = xr[g * 2];
            nfloat4 v1 = xr[g * 2 + 1];
            *(uint4*)&Ar[g * 8] = __builtin_bit_cast(uint4, cvt8(v0, v1));
        }
#pragma unroll
        for (int it = 0; it < 4; ++it) {
            const int g = lq + it * 4;
            nfloat4 v0 = __builtin_nontemporal_load(ar + g * 2);
            nfloat4 v1 = __builtin_nontemporal_load(ar + g * 2 + 1);
            *(uint4*)&Ar[128 + g * 8] = __builtin_bit_cast(uint4, cvt8(v0, v1));
        }
    }
    lds_fence();   // own-wave staging writes visible before a1 reads

    // ---- a1 frags (chunk is dead for writes after these 8 reads) ----
    unsigned short* Tw = At + wave * 16 * 264;       // own chunk base
    bf16x8 a1[8];
#pragma unroll
    for (int ks = 0; ks < 8; ++ks)
        a1[ks] = load_frag(&Tw[lm * 264 + ks * 32 + lq4 * 8]);

    // ---- GEMM1: [16 x 256] @ [256 x 128] ----
    floatx4 acc1[8];
#pragma unroll
    for (int ct = 0; ct < 8; ++ct) {
        floatx4 acc = {0.f, 0.f, 0.f, 0.f};
        const unsigned short* wr = wp1a + (ct * 8 * 64 + lane) * 8;
#pragma unroll
        for (int ks = 0; ks < 8; ++ks) {
            bf16x8 b = (ct == 0) ? bpre[ks] : load_frag(wr + ks * 512);
            acc = __builtin_amdgcn_mfma_f32_16x16x32_bf16(a1[ks], b, acc, 0, 0, 0);
        }
        acc1[ct] = acc;
    }

    // ---- preload GEMM2 ct=0 B-frags (fly under LN) ----
    bf16x8 b2pre[4];
#pragma unroll
    for (int ks = 0; ks < 4; ++ks)
        b2pre[ks] = load_frag(&wp1b[(ks * 64 + lane) * 8]);

    // ---- bias + ReLU + per-wave LayerNorm (shuffle over 16 lanes) ----
    float sum_[4] = {0, 0, 0, 0}, sq_[4] = {0, 0, 0, 0};
#pragma unroll
    for (int ct = 0; ct < 8; ++ct) {
        const float bb = b1a[ct * 16 + lm];
#pragma unroll
        for (int i = 0; i < 4; ++i) {
            float v = acc1[ct][i] + bb;
            v = fmaxf(v, 0.f);
            acc1[ct][i] = v;
            sum_[i] += v;
            sq_[i]  += v * v;
        }
    }
#pragma unroll
    for (int m = 1; m < 16; m <<= 1) {
#pragma unroll
        for (int i = 0; i < 4; ++i) {
            sum_[i] += __shfl_xor(sum_[i], m, 64);
            sq_[i]  += __shfl_xor(sq_[i],  m, 64);
        }
    }
    float mu[4], rs[4];
#pragma unroll
    for (int i = 0; i < 4; ++i) {
        mu[i] = sum_[i] * (1.f / NH);
        float var = sq_[i] * (1.f / NH) - mu[i] * mu[i];
        rs[i] = rsqrtf(var + LN_EPS);
    }

    // ---- LN apply -> Ttile (overwrites own dead Atile cols 0..127) ----
#pragma unroll
    for (int ct = 0; ct < 8; ++ct) {
        const int c = ct * 16 + lm;
        const float gg = g1[c], bb = be1[c];
#pragma unroll
        for (int i = 0; i < 4; ++i) {
            float nv = (acc1[ct][i] - mu[i]) * rs[i] * gg + bb;
            Tw[(lq4 * 4 + i) * 264 + c] = __builtin_bit_cast(unsigned short, (__bf16)nv);
        }
    }
    lds_fence();   // Ttile writes visible before a2 reads

    bf16x8 a2[4];
#pragma unroll
    for (int ks = 0; ks < 4; ++ks)
        a2[ks] = load_frag(&Tw[lm * 264 + ks * 32 + lq4 * 8]);

    // ---- GEMM2: [16 x 128] @ [128 x 128] -> f32 accbuf (stride 132) ----
#pragma unroll
    for (int ct = 0; ct < 8; ++ct) {
        floatx4 acc = {0.f, 0.f, 0.f, 0.f};
        const unsigned short* wr = wp1b + (ct * 4 * 64 + lane) * 8;
#pragma unroll
        for (int ks = 0; ks < 4; ++ks) {
            bf16x8 b = (ct == 0) ? b2pre[ks] : load_frag(wr + ks * 512);
            acc = __builtin_amdgcn_mfma_f32_16x16x32_bf16(a2[ks], b, acc, 0, 0, 0);
        }
        const int c = ct * 16 + lm;
#pragma unroll
        for (int i = 0; i < 4; ++i) {
            const int r = wave * 16 + lq4 * 4 + i;
            smem[r * 132 + c] = acc[i];   // bank=(4r+c)%32: 2-way, free
        }
    }
    __syncthreads();   // the ONE true cross-wave barrier

    // ---- segmented reduction over the block's 64 sorted edges ----
    {
        const int t = threadIdx.x;
        const int cc = t & 127;
        const int jb = (t >> 7) * 32;
        float a = 0.f;
        int cur = rows_s[jb];
#pragma unroll 4
        for (int j = jb; j < jb + 32; ++j) {
            a += smem[j * 132 + cc];      // bank=(4j+cc)%32: 2-way, free
            int nxt = (j + 1 < jb + 32) ? rows_s[j + 1] : -1;
            if (nxt != cur) {
                atomicAdd(&sums[cur * NH + cc], a);
                a = 0.f;
                cur = nxt;
            }
        }
    }
}

// ---------------------------------------------------------------------------
// Node MLP: A = [x[n] | sums[n]/cnt + b1b (cnt>0)], packed weights.
// ---------------------------------------------------------------------------
__global__ __launch_bounds__(256) void node_mlp_kernel(
    const float* __restrict__ x,
    const float* __restrict__ sums, const int* __restrict__ row_start,
    const float* __restrict__ b1b,
    const unsigned short* __restrict__ wp2a, const float* __restrict__ b2a,
    const float* __restrict__ g2, const float* __restrict__ be2,
    const unsigned short* __restrict__ wp2b, const float* __restrict__ b2b,
    float* __restrict__ out)
{
    __shared__ unsigned short Atile[4][16][KA + 8];
    __shared__ unsigned short Ttile[4][16][NH + 8];

    const int wave = threadIdx.x >> 6;
    const int lane = threadIdx.x & 63;
    const int n0 = blockIdx.x * 64 + wave * 16;

    {
        const int lrow = lane >> 2;
        const int lq   = lane & 3;
        int n = n0 + lrow;
        if (n >= NN) n = NN - 1;
        const int cntn = row_start[n + 1] - row_start[n];
        const float inv  = (cntn > 0) ? (1.f / (float)cntn) : 1.f;
        const float addb = (cntn > 0) ? 1.f : 0.f;
        const float4* xr = (const float4*)(x + n * NF);
        const float4* sr = (const float4*)(sums + n * NH);
        const float4* br = (const float4*)b1b;
        unsigned short* Ar = &Atile[wave][lrow][0];
#pragma unroll
        for (int it = 0; it < 8; ++it) {
            int c4 = lq + it * 4;
            float4 v = xr[c4];
            uint2 w;
            w.x = (unsigned)f2bf(v.x) | ((unsigned)f2bf(v.y) << 16);
            w.y = (unsigned)f2bf(v.z) | ((unsigned)f2bf(v.w) << 16);
            *(uint2*)&Ar[c4 * 4] = w;
            float4 v2 = sr[c4];
            float4 bv = br[c4];
            float a0 = v2.x * inv + addb * bv.x;
            float a1 = v2.y * inv + addb * bv.y;
            float a2 = v2.z * inv + addb * bv.z;
            float a3 = v2.w * inv + addb * bv.w;
            uint2 w2;
            w2.x = (unsigned)f2bf(a0) | ((unsigned)f2bf(a1) << 16);
            w2.y = (unsigned)f2bf(a2) | ((unsigned)f2bf(a3) << 16);
            *(uint2*)&Ar[128 + c4 * 4] = w2;
        }
    }
    __syncthreads();

    const int lm  = lane & 15;
    const int lq4 = lane >> 4;

    bf16x8 a1[8];
#pragma unroll
    for (int ks = 0; ks < 8; ++ks)
        a1[ks] = load_frag(&Atile[wave][lm][ks * 32 + lq4 * 8]);

    floatx4 acc1[8];
#pragma unroll
    for (int ct = 0; ct < 8; ++ct) {
        floatx4 acc = {0.f, 0.f, 0.f, 0.f};
        const unsigned short* wr = wp2a + (ct * 8 * 64 + lane) * 8;
#pragma unroll
        for (int ks = 0; ks < 8; ++ks) {
            bf16x8 b = load_frag(wr + ks * 512);
            acc = __builtin_amdgcn_mfma_f32_16x16x32_bf16(a1[ks], b, acc, 0, 0, 0);
        }
        acc1[ct] = acc;
    }

    float sum_[4] = {0, 0, 0, 0}, sq_[4] = {0, 0, 0, 0};
#pragma unroll
    for (int ct = 0; ct < 8; ++ct) {
        const float bb = b2a[ct * 16 + lm];
#pragma unroll
        for (int i = 0; i < 4; ++i) {
            float v = acc1[ct][i] + bb;
            v = fmaxf(v, 0.f);
            acc1[ct][i] = v;
            sum_[i] += v;
            sq_[i]  += v * v;
        }
    }
#pragma unroll
    for (int m = 1; m < 16; m <<= 1) {
#pragma unroll
        for (int i = 0; i < 4; ++i) {
            sum_[i] += __shfl_xor(sum_[i], m, 64);
            sq_[i]  += __shfl_xor(sq_[i],  m, 64);
        }
    }
    float mu[4], rs[4];
#pragma unroll
    for (int i = 0; i < 4; ++i) {
        mu[i] = sum_[i] * (1.f / NH);
        float var = sq_[i] * (1.f / NH) - mu[i] * mu[i];
        rs[i] = rsqrtf(var + LN_EPS);
    }
#pragma unroll
    for (int ct = 0; ct < 8; ++ct) {
        const int c = ct * 16 + lm;
        const float gg = g2[c], bb = be2[c];
#pragma unroll
        for (int i = 0; i < 4; ++i) {
            float nv = (acc1[ct][i] - mu[i]) * rs[i] * gg + bb;
            Ttile[wave][lq4 * 4 + i][c] = f2bf(nv);
        }
    }
    __syncthreads();

    bf16x8 a2[4];
#pragma unroll
    for (int ks = 0; ks < 4; ++ks)
        a2[ks] = load_frag(&Ttile[wave][lm][ks * 32 + lq4 * 8]);

#pragma unroll
    for (int ct = 0; ct < 8; ++ct) {
        floatx4 acc = {0.f, 0.f, 0.f, 0.f};
        const unsigned short* wr = wp2b + (ct * 4 * 64 + lane) * 8;
#pragma unroll
        for (int ks = 0; ks < 4; ++ks) {
            bf16x8 b = load_frag(wr + ks * 512);
            acc = __builtin_amdgcn_mfma_f32_16x16x32_bf16(a2[ks], b, acc, 0, 0, 0);
        }
        const int c = ct * 16 + lm;
        const float bb = b2b[c];
#pragma unroll
        for (int i = 0; i < 4; ++i) {
            int n = n0 + lq4 * 4 + i;
            if (n < NN) out[n * NT + c] = acc[i] + bb;
        }
    }
}

// ---------------------------------------------------------------------------
// Workspace layout (bytes):
//   [0,          5,120,000)  sums      f32 [10000][128]
//   [5,120,000,  5,160,000)  hist      int [10000]
//   [5,160,000,  5,200,000)  cursor    int [10000]
//   [5,200,000,  5,240,064)  row_start int [10001] (padded)
//   [5,240,064,  7,800,064)  perm      int [640000]
//   [7,800,064,  7,865,600)  wp1a      bf16 frag-packed [64 frags][64 lanes][8]
//   [7,865,600,  7,898,368)  wp1b      bf16 frag-packed [32][64][8]
//   [7,898,368,  7,963,904)  wp2a      bf16 frag-packed [64][64][8]
//   [7,963,904,  7,996,672)  wp2b      bf16 frag-packed [32][64][8]
// ---------------------------------------------------------------------------
extern "C" void kernel_launch(void* const* d_in, const int* in_sizes, int n_in,
                              void* d_out, int out_size, void* d_ws, size_t ws_size,
                              hipStream_t stream) {
    const float* x     = (const float*)d_in[0];
    const int*   eidx  = (const int*)d_in[1];
    const float* eattr = (const float*)d_in[2];
    const float* W1a = (const float*)d_in[3];
    const float* b1a = (const float*)d_in[4];
    const float* g1  = (const float*)d_in[5];
    const float* be1 = (const float*)d_in[6];
    const float* W1b = (const float*)d_in[7];
    const float* b1b = (const float*)d_in[8];
    const float* W2a = (const float*)d_in[9];
    const float* b2a = (const float*)d_in[10];
    const float* g2  = (const float*)d_in[11];
    const float* be2 = (const float*)d_in[12];
    const float* W2b = (const float*)d_in[13];
    const float* b2b = (const float*)d_in[14];

    char* ws = (char*)d_ws;
    float* sums     = (float*)ws;
    int*   hist     = (int*)(ws + 5120000);
    int*   cursor   = (int*)(ws + 5160000);
    int*   row_start= (int*)(ws + 5200000);
    int*   perm     = (int*)(ws + 5240064);
    unsigned short* wp1a = (unsigned short*)(ws + 7800064);
    unsigned short* wp1b = (unsigned short*)(ws + 7865600);
    unsigned short* wp2a = (unsigned short*)(ws + 7898368);
    unsigned short* wp2b = (unsigned short*)(ws + 7963904);

    const int* erow = eidx;
    const int* ecol = eidx + NE;

    (void)hipMemsetAsync(ws, 0, 5160000, stream);   // zero sums + hist
    conv_weights<<<48, 256, 0, stream>>>(W1a, W1b, W2a, W2b, wp1a, wp1b, wp2a, wp2b);
    hist_kernel<<<(NE + 255) / 256, 256, 0, stream>>>(erow, hist);
    scan_kernel<<<1, 256, 0, stream>>>(hist, row_start, cursor);
    scatter_kernel<<<(NE + 255) / 256, 256, 0, stream>>>(erow, cursor, perm);
    edge_mlp_kernel<<<NE / 64, 256, 0, stream>>>(x, erow, ecol, eattr, perm,
                                                 wp1a, b1a, g1, be1, wp1b, sums);
    node_mlp_kernel<<<(NN + 63) / 64, 256, 0, stream>>>(x, sums, row_start, b1b,
                                                        wp2a, b2a, g2, be2, wp2b, b2b,
                                                        (float*)d_out);
}